// Round 3
// baseline (499.483 us; speedup 1.0000x reference)
//
#include <hip/hip_runtime.h>
#include <stdint.h>

// LSTM cell as one bf16-MFMA GEMM: M=65536, N=1024 (4 gates x 256), K=512 (x||h)
// R4: 256x256 8-phase schedule (T3+T4+T5). 8 waves, BK=64, 2x(A32KB+B32KB) LDS.
// Phases = C-quadrants (Ahalf qa, Bhalf qb): per-wave output is interleaved
// across both halves (rows wr*64 in each A-half, cols wc*32 in each B-half) so
// each half-tile dies progressively and its slot is restaged mid-tile:
//   p1: compute (A0,B0), stage A1(kt+1)   p2: (A0,B1), stage B1(kt+1)
//   p3: (A1,B0), stage A0(kt+2)           p4: (A1,B1), stage B0(kt+2)
// Counted s_waitcnt vmcnt(4) once per K-tile (raw s_barrier everywhere: no
// __syncthreads vmcnt(0) drain). Every half staged >=4 phases before use.
// W-row map per tile col c: n = (2*(c>>7)+((c>>4)&1))*256 + h0 + ((c>>5)&3)*16
// + (c&15)  -> wave (wr,wc) frag (qb,f) = gate 2qb+f at h = h0+wc*16+m
// => register LSTM epilogue preserved. LDS swizzle: byte ^= (row&7)<<4 (G4).
#define B_DIM 65536
#define HOFF  16777216   // B_DIM*256, offset of c_new in d_out

typedef __attribute__((ext_vector_type(8))) short short8;
typedef __attribute__((ext_vector_type(8))) unsigned short ushort8_t;
typedef __attribute__((ext_vector_type(4))) float f32x4;

__device__ __forceinline__ unsigned short f2bf(float f) {
  unsigned int u = __builtin_bit_cast(unsigned int, f);
  u += 0x7FFFu + ((u >> 16) & 1u);          // RNE
  return (unsigned short)(u >> 16);
}
__device__ __forceinline__ float sigf(float x) { return 1.0f / (1.0f + __expf(-x)); }
__device__ __forceinline__ float tanh_fast(float x) {
  float a = fabsf(x);
  float e = __expf(-2.0f * a);
  float t = (1.0f - e) / (1.0f + e);
  return x < 0.0f ? -t : t;
}

typedef const __attribute__((address_space(1))) unsigned int* as1p;
typedef __attribute__((address_space(3))) unsigned int* as3p;
__device__ __forceinline__ void llds16(const unsigned short* g, unsigned short* l) {
  __builtin_amdgcn_global_load_lds((as1p)g, (as3p)l, 16, 0, 0);
}

// ---- prep: fp32 -> bf16, 8 elems/thread, 16B-aligned loads/stores ----------
__global__ void prep_a(const float* __restrict__ x, const float* __restrict__ h,
                       ushort8_t* __restrict__ A8) {
  unsigned o = blockIdx.x * 256u + threadIdx.x;   // [0, B*64)
  unsigned b = o >> 6, c8 = o & 63u;
  const float* src = (c8 < 32u) ? x + (size_t)b * 256u + c8 * 8u
                                : h + (size_t)b * 256u + (c8 - 32u) * 8u;
  float4 v0 = *(const float4*)src;
  float4 v1 = *(const float4*)(src + 4);
  ushort8_t p;
  p[0] = f2bf(v0.x); p[1] = f2bf(v0.y); p[2] = f2bf(v0.z); p[3] = f2bf(v0.w);
  p[4] = f2bf(v1.x); p[5] = f2bf(v1.y); p[6] = f2bf(v1.z); p[7] = f2bf(v1.w);
  A8[o] = p;                                      // = A[b*512 + c8*8]
}

__global__ void prep_w(const float* __restrict__ Wi, const float* __restrict__ Wh,
                       ushort8_t* __restrict__ W8) {
  unsigned o = blockIdx.x * 256u + threadIdx.x;   // [0, 1024*64)
  unsigned n = o >> 6, c8 = o & 63u;
  const float* src = (c8 < 32u) ? Wi + (size_t)n * 256u + c8 * 8u
                                : Wh + (size_t)n * 256u + (c8 - 32u) * 8u;
  float4 v0 = *(const float4*)src;
  float4 v1 = *(const float4*)(src + 4);
  ushort8_t p;
  p[0] = f2bf(v0.x); p[1] = f2bf(v0.y); p[2] = f2bf(v0.z); p[3] = f2bf(v0.w);
  p[4] = f2bf(v1.x); p[5] = f2bf(v1.y); p[6] = f2bf(v1.z); p[7] = f2bf(v1.w);
  W8[o] = p;
}

// ---- fused GEMM + register LSTM epilogue, 256^2 8-phase --------------------
__global__ __launch_bounds__(512, 2) void lstm_gemm(
    const unsigned short* __restrict__ A,   // [B][512] bf16
    const unsigned short* __restrict__ W,   // [1024][512] bf16, row n=gate*256+h
    const float* __restrict__ cprev,
    const float* __restrict__ bi, const float* __restrict__ bh,
    float* __restrict__ out) {
  __shared__ __align__(16) char smem[131072];
  unsigned short* const sU = (unsigned short*)smem;
  // layout (ushorts): buf b at b*32768: A halves [0,8192)+[8192,16384),
  //                   B halves [16384,24576)+[24576,32768)

  const int t = threadIdx.x;
  const int wid = t >> 6, lane = t & 63;
  const int m = lane & 15, q = lane >> 4;
  const int wr = wid >> 2, wc = wid & 3;

  // XCD remap: 1024 blocks = 8 xcd * (32 m-tiles * 4 n-tiles); the 4 N-blocks
  // sharing an A-tile are consecutive on one XCD.
  const unsigned bid = blockIdx.x;
  const unsigned xcd = bid & 7u, idx = bid >> 3;
  const int b0 = (int)((xcd * 32u + (idx >> 2)) * 256u);
  const int h0 = (int)((idx & 3u) * 64u);

  // staging constants: half-tile = 128 rows x 64 bf16 = 16 segs of 1KB;
  // wave owns segs {2w,2w+1}. Lane l: row s*8 + (l>>3), global k-chunk
  // pre-swizzled: (l&7)^(l>>3)  (inverse of read-side byte ^= (row&7)<<4).
  const int l3 = lane >> 3;
  const unsigned ckg = (unsigned)((((lane & 7) ^ l3)) * 8);
  unsigned aSrc[2][2], bSrc[2][2];
#pragma unroll
  for (int hh = 0; hh < 2; ++hh)
#pragma unroll
    for (int j = 0; j < 2; ++j) {
      const int s = 2 * wid + j;
      aSrc[hh][j] = (unsigned)(b0 + hh * 128 + s * 8 + l3) * 512u + ckg;
      const int n = (2 * hh + ((s >> 1) & 1)) * 256 + h0 +
                    ((s >> 2) & 3) * 16 + (s & 1) * 8 + l3;
      bSrc[hh][j] = (unsigned)n * 512u + ckg;
    }
  const int dstSeg = 2 * wid * 512;   // wave's first segment (ushort offset)

  // frag-read constants (row = base + m; swizzled chunk = (kk*4+q)^(m&7))
  const int aBase = wr * 4096 + m * 64;   // (wr*64 + m)*64
  const int bBase = wc * 2048 + m * 64;   // (wc*32 + m)*64
  const int c0 = ((q) ^ (m & 7)) * 8;
  const int c1 = ((4 + q) ^ (m & 7)) * 8;

  const int hcol = h0 + wc * 16 + m;      // this lane's h column

  // accumulators pre-seeded with bias: acc[mi][gate], mi = qa*4+fi
  f32x4 acc[8][4];
#pragma unroll
  for (int g = 0; g < 4; ++g) {
    float bvv = bi[(g << 8) + hcol] + bh[(g << 8) + hcol];
    f32x4 z = {bvv, bvv, bvv, bvv};
#pragma unroll
    for (int mi = 0; mi < 8; ++mi) acc[mi][g] = z;
  }

  short8 av[4][2], bv[2][2];
  float cv[8][4];

  auto stA = [&](int buf, int ha, int kt) {
    unsigned short* d = sU + buf * 32768 + ha * 8192 + dstSeg;
    const unsigned ko = (unsigned)kt * 64u;
    llds16(A + aSrc[ha][0] + ko, d);
    llds16(A + aSrc[ha][1] + ko, d + 512);
  };
  auto stB = [&](int buf, int hb, int kt) {
    unsigned short* d = sU + buf * 32768 + 16384 + hb * 8192 + dstSeg;
    const unsigned ko = (unsigned)kt * 64u;
    llds16(W + bSrc[hb][0] + ko, d);
    llds16(W + bSrc[hb][1] + ko, d + 512);
  };
  auto rdA = [&](int buf, int qa) {
    const unsigned short* p = sU + buf * 32768 + qa * 8192 + aBase;
#pragma unroll
    for (int fi = 0; fi < 4; ++fi) {
      av[fi][0] = *(const short8*)(p + fi * 1024 + c0);
      av[fi][1] = *(const short8*)(p + fi * 1024 + c1);
    }
  };
  auto rdB = [&](int buf, int qb) {
    const unsigned short* p = sU + buf * 32768 + 16384 + qb * 8192 + bBase;
#pragma unroll
    for (int f = 0; f < 2; ++f) {
      bv[f][0] = *(const short8*)(p + f * 1024 + c0);
      bv[f][1] = *(const short8*)(p + f * 1024 + c1);
    }
  };
  auto mm = [&](int mi0, int nj0) {
    __builtin_amdgcn_s_setprio(1);
#pragma unroll
    for (int fi = 0; fi < 4; ++fi)
#pragma unroll
      for (int f = 0; f < 2; ++f)
#pragma unroll
        for (int kk = 0; kk < 2; ++kk)
          acc[mi0 + fi][nj0 + f] = __builtin_amdgcn_mfma_f32_16x16x32_bf16(
              av[fi][kk], bv[f][kk], acc[mi0 + fi][nj0 + f], 0, 0, 0);
    __builtin_amdgcn_s_setprio(0);
  };
  auto bar = [&] {
    __builtin_amdgcn_s_barrier();
    __builtin_amdgcn_sched_barrier(0);
  };

  // prologue: tile0 (4 halves) + A0,B0 of tile1; vmcnt(4) => tile0 landed,
  // A0(1)/B0(1) stay in flight.
  stA(0, 0, 0); stB(0, 0, 0); stA(0, 1, 0); stB(0, 1, 0);
  stA(1, 0, 1); stB(1, 0, 1);
  asm volatile("s_waitcnt vmcnt(4)" ::: "memory");
  bar();

#pragma unroll 2
  for (int kt = 0; kt < 8; ++kt) {
    const int cur = kt & 1;
    // ---- p1: (A0,B0); stage A1(kt+1) -> buf^1 ----
    rdA(cur, 0); rdB(cur, 0);
    if (kt < 7) stA(cur ^ 1, 1, kt + 1);
    if (kt == 7) {   // stages all done: prefetch cprev (4 phases of cover)
#pragma unroll
      for (int mi = 0; mi < 8; ++mi) {
        const int br = b0 + (mi >> 2) * 128 + wr * 64 + (mi & 3) * 16 + (q << 2);
#pragma unroll
        for (int r = 0; r < 4; ++r)
          cv[mi][r] = cprev[(size_t)(br + r) * 256 + hcol];
      }
    }
    bar();
    mm(0, 0);
    bar();
    // ---- p2: (A0,B1) [av reused]; stage B1(kt+1) ----
    rdB(cur, 1);
    if (kt < 7) stB(cur ^ 1, 1, kt + 1);
    bar();
    mm(0, 2);
    bar();
    // ---- p3: (A1,B0); stage A0(kt+2) over dead A0(kt) ----
    rdA(cur, 1); rdB(cur, 0);
    if (kt < 6) stA(cur, 0, kt + 2);
    bar();
    mm(4, 0);
    bar();
    // ---- p4: (A1,B1); stage B0(kt+2) over dead B0(kt) ----
    rdB(cur, 1);
    if (kt < 6) stB(cur, 0, kt + 2);
    bar();
    mm(4, 2);
    // counted wait: leaves the last 2 half-tiles (kt+2's A0,B0) in flight.
    if (kt < 6) asm volatile("s_waitcnt vmcnt(4)" ::: "memory");
    else if (kt == 6) asm volatile("s_waitcnt vmcnt(0)" ::: "memory");
    bar();
  }

  // drain everything (incl. cv loads) before LDS reuse
  asm volatile("s_waitcnt vmcnt(0) lgkmcnt(0)" ::: "memory");
  bar();

  // ---- epilogue: gates -> (h_new, c_new); LDS-staged full-line stores ------
  // pass 1: compute, keep c_new in regs, stage h_new in [256][68] fp32 (68 ->
  // 16B-aligned rows, bank-spread); cooperative 256B-per-16-lane stores.
  float* ep = (float*)smem;
  float cn[8][4];
#pragma unroll
  for (int mi = 0; mi < 8; ++mi) {
    const int row = (mi >> 2) * 128 + wr * 64 + (mi & 3) * 16 + (q << 2);
#pragma unroll
    for (int r = 0; r < 4; ++r) {
      float iv = sigf(acc[mi][0][r]);
      float fv = sigf(acc[mi][1][r]);
      float gv = tanh_fast(acc[mi][2][r]);
      float ov = sigf(acc[mi][3][r]);
      float c2 = fv * cv[mi][r] + iv * gv;
      cn[mi][r] = c2;
      ep[(row + r) * 68 + wc * 16 + m] = ov * tanh_fast(c2);
    }
  }
  asm volatile("s_waitcnt lgkmcnt(0)" ::: "memory");
  bar();
#pragma unroll
  for (int k = 0; k < 8; ++k) {
    const int id = t + k * 512;                   // [0,4096)
    const int row = id >> 4, c4 = id & 15;
    *(float4*)(out + ((size_t)(b0 + row) << 8) + h0 + c4 * 4) =
        *(const float4*)&ep[row * 68 + c4 * 4];
  }
  asm volatile("s_waitcnt lgkmcnt(0)" ::: "memory");
  bar();
#pragma unroll
  for (int mi = 0; mi < 8; ++mi) {
    const int row = (mi >> 2) * 128 + wr * 64 + (mi & 3) * 16 + (q << 2);
#pragma unroll
    for (int r = 0; r < 4; ++r)
      ep[(row + r) * 68 + wc * 16 + m] = cn[mi][r];
  }
  asm volatile("s_waitcnt lgkmcnt(0)" ::: "memory");
  bar();
#pragma unroll
  for (int k = 0; k < 8; ++k) {
    const int id = t + k * 512;
    const int row = id >> 4, c4 = id & 15;
    *(float4*)(out + HOFF + ((size_t)(b0 + row) << 8) + h0 + c4 * 4) =
        *(const float4*)&ep[row * 68 + c4 * 4];
  }
}

// ---- fallback (tiny workspace): correct but slow fp32 path -----------------
__global__ void lstm_naive(const float* __restrict__ x, const float* __restrict__ h,
                           const float* __restrict__ c,
                           const float* __restrict__ Wi, const float* __restrict__ Wh,
                           const float* __restrict__ bi, const float* __restrict__ bh,
                           float* __restrict__ out) {
  int gid = blockIdx.x * 256 + threadIdx.x;
  int b = gid >> 8, hh = gid & 255;
  float a0 = bi[hh] + bh[hh];
  float a1 = bi[256 + hh] + bh[256 + hh];
  float a2 = bi[512 + hh] + bh[512 + hh];
  float a3 = bi[768 + hh] + bh[768 + hh];
  const float* xr = x + (size_t)b * 256;
  const float* hr = h + (size_t)b * 256;
  const float* w0 = Wi + (size_t)hh * 256;
  const float* w1 = Wh + (size_t)hh * 256;
  for (int i = 0; i < 256; ++i) {
    float xv = xr[i];
    a0 += xv * w0[i]; a1 += xv * w0[65536 + i];
    a2 += xv * w0[131072 + i]; a3 += xv * w0[196608 + i];
  }
  for (int i = 0; i < 256; ++i) {
    float hv = hr[i];
    a0 += hv * w1[i]; a1 += hv * w1[65536 + i];
    a2 += hv * w1[131072 + i]; a3 += hv * w1[196608 + i];
  }
  float iv = sigf(a0), fv = sigf(a1), gv = tanh_fast(a2), ov = sigf(a3);
  float cn = fv * c[gid] + iv * gv;
  out[gid] = ov * tanh_fast(cn);
  out[HOFF + gid] = cn;
}

extern "C" void kernel_launch(void* const* d_in, const int* in_sizes, int n_in,
                              void* d_out, int out_size, void* d_ws, size_t ws_size,
                              hipStream_t stream) {
  const float* x  = (const float*)d_in[0];
  const float* h  = (const float*)d_in[1];
  const float* c  = (const float*)d_in[2];
  const float* Wi = (const float*)d_in[3];
  const float* Wh = (const float*)d_in[4];
  const float* bi = (const float*)d_in[5];
  const float* bh = (const float*)d_in[6];
  float* out = (float*)d_out;

  const size_t needA = (size_t)B_DIM * 512 * 2;   // 64 MB bf16 A = x||h
  const size_t needW = (size_t)1024 * 512 * 2;    // 1 MB bf16 W
  if (ws_size >= needA + needW) {
    ushort8_t* A8 = (ushort8_t*)d_ws;
    ushort8_t* W8 = (ushort8_t*)((char*)d_ws + needA);
    hipLaunchKernelGGL(prep_a, dim3(B_DIM * 64 / 256), dim3(256), 0, stream, x, h, A8);
    hipLaunchKernelGGL(prep_w, dim3(1024 * 64 / 256), dim3(256), 0, stream, Wi, Wh, W8);
    hipLaunchKernelGGL(lstm_gemm, dim3((B_DIM / 256) * 4), dim3(512), 0, stream,
                       (const unsigned short*)A8, (const unsigned short*)W8,
                       c, bi, bh, out);
  } else {
    hipLaunchKernelGGL(lstm_naive, dim3(B_DIM), dim3(256), 0, stream,
                       x, h, c, Wi, Wh, bi, bh, out);
  }
}